// Round 2
// baseline (116.530 us; speedup 1.0000x reference)
//
#include <hip/hip_runtime.h>

// out[b,e,j] = bias[j] + sum_k weight[k,j] * y[b, e+k-7, j]
// y[b,e',j]  = sum_{i<=j} x[b,e',i] * dv^(j-i)   (decayed prefix scan over features)
// dv = clip(decay_value[1], 0.9, 1.0); y rows with e' < 0 are zero (causal padding).
//
// Split design: kernel 1 streams x -> y (workspace), one wave per row, no LDS,
// high occupancy to hide the scan's shfl dependency chain. Kernel 2 streams
// y -> out, one thread per output float4; tap re-reads hit L2/L3.

#define B_    8
#define E_    2048
#define DIM_  512
#define K_    8

// ---------------- Kernel 1: decayed prefix scan along features ----------------
// One wave per (b,e) row; 8 contiguous floats per lane; Kogge-Stone carry.
__global__ __launch_bounds__(256) void krl_scan(
    const float* __restrict__ x,
    const float* __restrict__ decay,
    float* __restrict__ y)
{
    const int t    = threadIdx.x;
    const int lane = t & 63;
    const int wave = t >> 6;
    const int row  = blockIdx.x * 4 + wave;   // row in [0, B*E)

    float dv = decay[1];
    dv = fminf(fmaxf(dv, 0.9f), 1.0f);
    const float dv2 = dv * dv;
    const float dv4 = dv2 * dv2;
    const float dv8 = dv4 * dv4;

    const float4* xp = (const float4*)(x + (size_t)row * DIM_ + lane * 8);
    const float4 a0 = xp[0];
    const float4 a1 = xp[1];
    const float xv[8] = {a0.x, a0.y, a0.z, a0.w, a1.x, a1.y, a1.z, a1.w};

    float tl[8];
    tl[0] = xv[0];
    #pragma unroll
    for (int m = 1; m < 8; ++m) tl[m] = fmaf(dv, tl[m - 1], xv[m]);

    // cross-lane: Y_l = T_l + dv^8 * Y_{l-1}
    float v  = tl[7];
    float ap = dv8;
    #pragma unroll
    for (int off = 1; off < 64; off <<= 1) {
        float up = __shfl_up(v, off, 64);
        if (lane >= off) v = fmaf(ap, up, v);
        ap *= ap;
    }
    float carry = __shfl_up(v, 1, 64);
    if (lane == 0) carry = 0.f;
    float dp = dv;
    #pragma unroll
    for (int m = 0; m < 8; ++m) { tl[m] = fmaf(dp, carry, tl[m]); dp *= dv; }

    float4* yp = (float4*)(y + (size_t)row * DIM_ + lane * 8);
    yp[0] = make_float4(tl[0], tl[1], tl[2], tl[3]);
    yp[1] = make_float4(tl[4], tl[5], tl[6], tl[7]);
}

// ---------------- Kernel 2: depthwise causal conv (K=8) along E ----------------
// One thread per output float4. Consecutive lanes -> consecutive feature chunks.
__global__ __launch_bounds__(256) void krl_conv(
    const float* __restrict__ y,
    const float* __restrict__ weight,
    const float* __restrict__ bias,
    float* __restrict__ out)
{
    const int gid   = blockIdx.x * 256 + threadIdx.x;   // [0, B*E*128)
    const int chunk = gid & 127;                        // feature float4 index
    const int e     = (gid >> 7) & (E_ - 1);
    const int b     = gid >> 18;
    const int jf    = chunk * 4;

    float4 acc = *(const float4*)(bias + jf);

    #pragma unroll
    for (int k = 0; k < K_; ++k) {
        const int eg = e + k - (K_ - 1);
        if (eg >= 0) {
            const float4 w  = *(const float4*)(weight + k * DIM_ + jf);
            const float4 yv = *(const float4*)(y + ((size_t)b * E_ + eg) * DIM_ + jf);
            acc.x = fmaf(w.x, yv.x, acc.x);
            acc.y = fmaf(w.y, yv.y, acc.y);
            acc.z = fmaf(w.z, yv.z, acc.z);
            acc.w = fmaf(w.w, yv.w, acc.w);
        }
    }
    *(float4*)(out + ((size_t)b * E_ + e) * DIM_ + jf) = acc;
}

extern "C" void kernel_launch(void* const* d_in, const int* in_sizes, int n_in,
                              void* d_out, int out_size, void* d_ws, size_t ws_size,
                              hipStream_t stream) {
    const float* x      = (const float*)d_in[0];
    const float* weight = (const float*)d_in[1];
    const float* bias   = (const float*)d_in[2];
    const float* decay  = (const float*)d_in[3];
    float* out = (float*)d_out;
    float* y   = (float*)d_ws;   // B*E*DIM floats = 33.5 MB (ws ~256 MB)

    krl_scan<<<dim3((B_ * E_) / 4), dim3(256), 0, stream>>>(x, decay, y);
    krl_conv<<<dim3((B_ * E_ * (DIM_ / 4)) / 256), dim3(256), 0, stream>>>(y, weight, bias, out);
}

// Round 3
// 109.317 us; speedup vs baseline: 1.0660x; 1.0660x over previous
//
#include <hip/hip_runtime.h>

// out[b,e,j] = bias[j] + sum_k weight[k,j] * y[b, e+k-7, j]
// y[b,e',j]  = sum_{i<=j} x[b,e',i] * dv^(j-i)   (decayed prefix scan over features)
// dv = clip(decay_value[1], 0.9, 1.0); y rows with e' < 0 are zero (causal padding).
//
// Fused v2: single kernel, 64 KB LDS tile (25 outputs + 7 halo rows), 512 threads
// (8 waves) per block -> 2 blocks/CU x 8 waves = 4 waves/SIMD to hide the scan's
// load->FMA->shfl dependency chain. Split-kernel variant (R2) regressed: y round-trip
// through HBM + cross-XCD L2 duplication of the 8x tap re-reads.

#define B_    8
#define E_    2048
#define DIM_  512
#define K_    8
#define TILE_E 25
#define NROWS  (TILE_E + K_ - 1)   // 32 rows -> 64 KB LDS, 2 blocks/CU

__global__ __launch_bounds__(512, 4) void krl_fused(
    const float* __restrict__ x,
    const float* __restrict__ weight,
    const float* __restrict__ bias,
    const float* __restrict__ decay,
    float* __restrict__ out)
{
    __shared__ float yls[NROWS][DIM_];

    const int tile = blockIdx.x;
    const int b    = blockIdx.y;
    const int e0   = tile * TILE_E;
    const int nout = min(TILE_E, E_ - e0);
    const int nscan = nout + K_ - 1;

    const int t    = threadIdx.x;
    const int lane = t & 63;
    const int wave = t >> 6;

    float dv = decay[1];
    dv = fminf(fmaxf(dv, 0.9f), 1.0f);
    const float dv2 = dv * dv;
    const float dv4 = dv2 * dv2;
    const float dv8 = dv4 * dv4;

    // Phase-2 operands loaded early (independent of LDS) to overlap phase 1.
    const int jf = (t & 127) * 4;
    float4 w[K_];
    #pragma unroll
    for (int k = 0; k < K_; ++k) w[k] = *(const float4*)(weight + k * DIM_ + jf);
    const float4 bi = *(const float4*)(bias + jf);

    // ---- Phase 1: decayed prefix scan along features; one row per wave-iter ----
    // LDS row r <-> e_global = e0 - 7 + r. 8 waves cover 32 rows in 4 iters each.
    for (int r = wave; r < nscan; r += 8) {
        const int eg = e0 - (K_ - 1) + r;
        float tl[8];
        if (eg >= 0) {
            const float4* xp = (const float4*)(x + ((size_t)b * E_ + eg) * DIM_ + lane * 8);
            const float4 a0 = xp[0];
            const float4 a1 = xp[1];
            const float xv[8] = {a0.x, a0.y, a0.z, a0.w, a1.x, a1.y, a1.z, a1.w};
            // lane-local scan over 8 contiguous features
            tl[0] = xv[0];
            #pragma unroll
            for (int m = 1; m < 8; ++m) tl[m] = fmaf(dv, tl[m - 1], xv[m]);
            // cross-lane recurrence Y_l = T_l + dv^8 * Y_{l-1} (Kogge-Stone)
            float v  = tl[7];
            float ap = dv8;
            #pragma unroll
            for (int off = 1; off < 64; off <<= 1) {
                float up = __shfl_up(v, off, 64);
                if (lane >= off) v = fmaf(ap, up, v);
                ap *= ap;
            }
            float carry = __shfl_up(v, 1, 64);   // y[8*lane - 1]
            if (lane == 0) carry = 0.f;
            float dp = dv;
            #pragma unroll
            for (int m = 0; m < 8; ++m) { tl[m] = fmaf(dp, carry, tl[m]); dp *= dv; }
        } else {
            #pragma unroll
            for (int m = 0; m < 8; ++m) tl[m] = 0.f;
        }
        float4* yp = (float4*)(&yls[r][lane * 8]);
        yp[0] = make_float4(tl[0], tl[1], tl[2], tl[3]);
        yp[1] = make_float4(tl[4], tl[5], tl[6], tl[7]);
    }
    __syncthreads();

    // ---- Phase 2: depthwise causal conv (K=8) along E, per feature chunk ----
    // Thread t owns feature chunk (t&127); rows (t>>7) + 4*i. Coalesced stores.
    for (int idx = t; idx < nout * 128; idx += 512) {
        const int te = idx >> 7;
        float4 acc = bi;
        #pragma unroll
        for (int k = 0; k < K_; ++k) {
            const float4 yv = *(const float4*)(&yls[te + k][jf]);
            acc.x = fmaf(w[k].x, yv.x, acc.x);
            acc.y = fmaf(w[k].y, yv.y, acc.y);
            acc.z = fmaf(w[k].z, yv.z, acc.z);
            acc.w = fmaf(w[k].w, yv.w, acc.w);
        }
        *(float4*)(out + ((size_t)b * E_ + e0 + te) * DIM_ + jf) = acc;
    }
}

extern "C" void kernel_launch(void* const* d_in, const int* in_sizes, int n_in,
                              void* d_out, int out_size, void* d_ws, size_t ws_size,
                              hipStream_t stream) {
    const float* x      = (const float*)d_in[0];
    const float* weight = (const float*)d_in[1];
    const float* bias   = (const float*)d_in[2];
    const float* decay  = (const float*)d_in[3];
    float* out = (float*)d_out;

    dim3 grid((E_ + TILE_E - 1) / TILE_E, B_);  // 82 x 8 = 656 blocks
    dim3 block(512);
    krl_fused<<<grid, block, 0, stream>>>(x, weight, bias, decay, out);
}

// Round 4
// 96.826 us; speedup vs baseline: 1.2035x; 1.1290x over previous
//
#include <hip/hip_runtime.h>

// out[b,e,j] = bias[j] + sum_k weight[k,j] * y[b, e+k-7, j]
// y[b,e',j]  = sum_{i<=j} x[b,e',i] * dv^(j-i)   (decayed prefix scan over features)
// dv = clip(decay_value[1], 0.9, 1.0); y rows with e' < 0 are zero (causal padding).
//
// R4: fused kernel, TILE_E=32 -> grid 64x8 = 512 blocks = exactly 2 blocks/CU
// (78 KB LDS each, 156 KB/CU) -> one perfectly balanced round, no scheduling
// tail (R1's 656 blocks on 512 slots gave a 1.5x wall on 144 CUs). Halo
// recompute down to 39/32 = 1.22x. 256 threads (4 waves) per block -- the
// 512-thread variant (R3) regressed: wider barrier domain + weight regs live
// across phase 1.

#define B_    8
#define E_    2048
#define DIM_  512
#define K_    8
#define TILE_E 32
#define NROWS  (TILE_E + K_ - 1)   // 39 rows * 2 KB = 79872 B LDS; 2 blocks/CU

__global__ __launch_bounds__(256) void krl_fused(
    const float* __restrict__ x,
    const float* __restrict__ weight,
    const float* __restrict__ bias,
    const float* __restrict__ decay,
    float* __restrict__ out)
{
    __shared__ float yls[NROWS][DIM_];

    const int tile = blockIdx.x;
    const int b    = blockIdx.y;
    const int e0   = tile * TILE_E;          // E_ % TILE_E == 0: no partial tiles

    const int t    = threadIdx.x;
    const int lane = t & 63;
    const int wave = t >> 6;

    float dv = decay[1];
    dv = fminf(fmaxf(dv, 0.9f), 1.0f);
    const float dv2 = dv * dv;
    const float dv4 = dv2 * dv2;
    const float dv8 = dv4 * dv4;

    // ---- Phase 1: decayed prefix scan along features; one row per wave-iter ----
    // LDS row r <-> e_global = e0 - 7 + r. Branch-free body (clamped address,
    // wave-uniform zero-fill) so the compiler can pipeline row r+4's load under
    // row r's shfl chain.
    for (int r = wave; r < NROWS; r += 4) {
        const int eg  = e0 - (K_ - 1) + r;
        const int egc = eg < 0 ? 0 : eg;
        const float4* xp = (const float4*)(x + ((size_t)b * E_ + egc) * DIM_ + lane * 8);
        float4 a0 = xp[0];
        float4 a1 = xp[1];
        if (eg < 0) {                        // wave-uniform, only tile 0
            a0 = make_float4(0.f, 0.f, 0.f, 0.f);
            a1 = a0;
        }
        const float xv[8] = {a0.x, a0.y, a0.z, a0.w, a1.x, a1.y, a1.z, a1.w};

        // lane-local scan over 8 contiguous features
        float tl[8];
        tl[0] = xv[0];
        #pragma unroll
        for (int m = 1; m < 8; ++m) tl[m] = fmaf(dv, tl[m - 1], xv[m]);

        // cross-lane recurrence Y_l = T_l + dv^8 * Y_{l-1} (Kogge-Stone)
        float v  = tl[7];
        float ap = dv8;
        #pragma unroll
        for (int off = 1; off < 64; off <<= 1) {
            float up = __shfl_up(v, off, 64);
            if (lane >= off) v = fmaf(ap, up, v);
            ap *= ap;
        }
        float carry = __shfl_up(v, 1, 64);   // y[8*lane - 1]
        if (lane == 0) carry = 0.f;
        float dp = dv;
        #pragma unroll
        for (int m = 0; m < 8; ++m) { tl[m] = fmaf(dp, carry, tl[m]); dp *= dv; }

        float4* yp = (float4*)(&yls[r][lane * 8]);
        yp[0] = make_float4(tl[0], tl[1], tl[2], tl[3]);
        yp[1] = make_float4(tl[4], tl[5], tl[6], tl[7]);
    }

    // Phase-2 operands: issue global loads before the barrier so their latency
    // hides under the barrier wait; after the loop so they don't occupy VGPRs
    // during phase 1.
    const int jf = (t & 127) * 4;
    float4 w[K_];
    #pragma unroll
    for (int k = 0; k < K_; ++k) w[k] = *(const float4*)(weight + k * DIM_ + jf);
    const float4 bi = *(const float4*)(bias + jf);

    __syncthreads();

    // ---- Phase 2: depthwise causal conv (K=8) along E, per feature chunk ----
    // Thread t owns feature chunk (t&127); row-group g = t>>7 interleaves rows.
    const int g = t >> 7;
    for (int te = g; te < TILE_E; te += 2) {
        float4 acc = bi;
        #pragma unroll
        for (int k = 0; k < K_; ++k) {
            const float4 yv = *(const float4*)(&yls[te + k][jf]);
            acc.x = fmaf(w[k].x, yv.x, acc.x);
            acc.y = fmaf(w[k].y, yv.y, acc.y);
            acc.z = fmaf(w[k].z, yv.z, acc.z);
            acc.w = fmaf(w[k].w, yv.w, acc.w);
        }
        *(float4*)(out + ((size_t)b * E_ + e0 + te) * DIM_ + jf) = acc;
    }
}

extern "C" void kernel_launch(void* const* d_in, const int* in_sizes, int n_in,
                              void* d_out, int out_size, void* d_ws, size_t ws_size,
                              hipStream_t stream) {
    const float* x      = (const float*)d_in[0];
    const float* weight = (const float*)d_in[1];
    const float* bias   = (const float*)d_in[2];
    const float* decay  = (const float*)d_in[3];
    float* out = (float*)d_out;

    dim3 grid(E_ / TILE_E, B_);   // 64 x 8 = 512 blocks == 2 blocks/CU exactly
    dim3 block(256);
    krl_fused<<<grid, block, 0, stream>>>(x, weight, bias, decay, out);
}

// Round 5
// 91.823 us; speedup vs baseline: 1.2691x; 1.0545x over previous
//
#include <hip/hip_runtime.h>

// out[b,e,j] = bias[j] + sum_k weight[k,j] * y[b, e+k-7, j]
// y[b,e',j]  = sum_{i<=j} x[b,e',i] * dv^(j-i)   (decayed prefix scan over features)
// dv = clip(decay_value[1], 0.9, 1.0); y rows with e' < 0 are zero (causal padding).
//
// R5: barrier-free register-window kernel. One WAVE owns 8 consecutive output
// rows of one b. It scans 15 x-rows (8 + 7 halo); each produced y-row is
// immediately folded into 8 rolling register accumulators (output e0+m takes
// tap w[r-m] from scan row r). Row r>=7 completes output e0+r-7 -> store.
// No LDS, no __syncthreads, all 2048 waves resident at once (2/SIMD).
// Halo x re-reads (1.875x) are L3-served; HBM stays at the 67 MB floor.

#define B_    8
#define E_    2048
#define DIM_  512
#define K_    8
#define SE_   8                     // output rows per wave
#define NR_   (SE_ + K_ - 1)        // 15 scan rows per wave

__global__ __launch_bounds__(256) void krl_win(
    const float* __restrict__ x,
    const float* __restrict__ weight,
    const float* __restrict__ bias,
    const float* __restrict__ decay,
    float* __restrict__ out)
{
    const int t    = threadIdx.x;
    const int lane = t & 63;
    const int wave = t >> 6;
    const int wid  = blockIdx.x * 4 + wave;      // [0, 2048)
    const int b    = wid >> 8;                   // E_/SE_ = 256 strips per b
    const int e0   = (wid & 255) << 3;

    float dv = decay[1];
    dv = fminf(fmaxf(dv, 0.9f), 1.0f);
    const float dv2 = dv * dv;
    const float dv4 = dv2 * dv2;
    const float dv8 = dv4 * dv4;

    const int jf = lane * 8;                     // 8 contiguous features per lane

    // Loop-invariant weights + bias in registers (L1-hot loads, issued once).
    float wv[K_][8];
    #pragma unroll
    for (int k = 0; k < K_; ++k) {
        const float4 p0 = *(const float4*)(weight + k * DIM_ + jf);
        const float4 p1 = *(const float4*)(weight + k * DIM_ + jf + 4);
        wv[k][0] = p0.x; wv[k][1] = p0.y; wv[k][2] = p0.z; wv[k][3] = p0.w;
        wv[k][4] = p1.x; wv[k][5] = p1.y; wv[k][6] = p1.z; wv[k][7] = p1.w;
    }
    const float4 bi0 = *(const float4*)(bias + jf);
    const float4 bi1 = *(const float4*)(bias + jf + 4);

    float a[SE_][8];
    #pragma unroll
    for (int m = 0; m < SE_; ++m)
        #pragma unroll
        for (int j = 0; j < 8; ++j) a[m][j] = 0.f;

    const float* xb = x + (size_t)b * E_ * DIM_ + jf;
    float*       ob = out + ((size_t)b * E_ + e0) * DIM_ + jf;

    #pragma unroll
    for (int r = 0; r < NR_; ++r) {
        const int eg = e0 - (K_ - 1) + r;        // scan-row index in E
        if (eg >= 0) {                           // wave-uniform (false only at e0=0)
            const float4* xp = (const float4*)(xb + (size_t)eg * DIM_);
            const float4 a0 = xp[0];
            const float4 a1 = xp[1];
            const float xv[8] = {a0.x, a0.y, a0.z, a0.w, a1.x, a1.y, a1.z, a1.w};

            // lane-local decayed scan over 8 contiguous features
            float tl[8];
            tl[0] = xv[0];
            #pragma unroll
            for (int m = 1; m < 8; ++m) tl[m] = fmaf(dv, tl[m - 1], xv[m]);

            // cross-lane: Y_l = T_l + dv^8 * Y_{l-1} (Kogge-Stone over 64 lanes)
            float v  = tl[7];
            float ap = dv8;
            #pragma unroll
            for (int off = 1; off < 64; off <<= 1) {
                float up = __shfl_up(v, off, 64);
                if (lane >= off) v = fmaf(ap, up, v);
                ap *= ap;
            }
            float carry = __shfl_up(v, 1, 64);   // y[jf - 1]
            if (lane == 0) carry = 0.f;
            float dp = dv;
            #pragma unroll
            for (int m = 0; m < 8; ++m) { tl[m] = fmaf(dp, carry, tl[m]); dp *= dv; }

            // fold y-row r into pending accumulators: output e0+m takes tap r-m
            const int mlo = (r - (K_ - 1)) < 0 ? 0 : (r - (K_ - 1));
            const int mhi = r < (SE_ - 1) ? r : (SE_ - 1);
            #pragma unroll
            for (int m = 0; m < SE_; ++m) {
                if (m >= mlo && m <= mhi) {      // static after unroll
                    const int k = r - m;
                    #pragma unroll
                    for (int j = 0; j < 8; ++j)
                        a[m][j] = fmaf(wv[k][j], tl[j], a[m][j]);
                }
            }
        }
        // output row e0 + (r-7) is complete after its last tap (scan row r)
        if (r >= K_ - 1) {
            const int m = r - (K_ - 1);
            float4 o0 = make_float4(a[m][0] + bi0.x, a[m][1] + bi0.y,
                                    a[m][2] + bi0.z, a[m][3] + bi0.w);
            float4 o1 = make_float4(a[m][4] + bi1.x, a[m][5] + bi1.y,
                                    a[m][6] + bi1.z, a[m][7] + bi1.w);
            *(float4*)(ob + (size_t)m * DIM_)     = o0;
            *(float4*)(ob + (size_t)m * DIM_ + 4) = o1;
        }
    }
}

extern "C" void kernel_launch(void* const* d_in, const int* in_sizes, int n_in,
                              void* d_out, int out_size, void* d_ws, size_t ws_size,
                              hipStream_t stream) {
    const float* x      = (const float*)d_in[0];
    const float* weight = (const float*)d_in[1];
    const float* bias   = (const float*)d_in[2];
    const float* decay  = (const float*)d_in[3];
    float* out = (float*)d_out;

    // 2048 waves = 512 blocks x 4 waves; no LDS, ~2 waves/SIMD -> all resident.
    krl_win<<<dim3((B_ * (E_ / SE_)) / 4), dim3(256), 0, stream>>>(
        x, weight, bias, decay, out);
}